// Round 4
// baseline (109.840 us; speedup 1.0000x reference)
//
#include <hip/hip_runtime.h>

#define L2E 1.44269504088896340736f

typedef float f32x4 __attribute__((ext_vector_type(4)));
typedef __bf16 bf16x8 __attribute__((ext_vector_type(8)));
typedef __bf16 bf16x4 __attribute__((ext_vector_type(4)));

// D(16x16)=A(16x32)*B(32x16)+C. A: lane l = row(l&15), k=8*(l>>4)+e.
// B: col(l&15), k=8*(l>>4)+e. C/D: col(l&15), row=4*(l>>4)+reg. [m89/m91]
__device__ inline void mfma_bf16(bf16x8 a, bf16x8 b, f32x4& c) {
    c = __builtin_amdgcn_mfma_f32_16x16x32_bf16(a, b, c, 0, 0, 0);
}

// ---------------- Kernel 1: Wh = h @ W, e_src, e_dst (unchanged) ----------------
__global__ __launch_bounds__(256, 2)
void k1_wh(const float* __restrict__ h, const float* __restrict__ W,
           const float* __restrict__ a, __bf16* __restrict__ whT,
           float* __restrict__ esrc, float* __restrict__ edst) {
    const int tid  = threadIdx.x;
    const int lane = tid & 63;
    const int w    = tid >> 6;
    const int blk  = blockIdx.x;
    const int r0   = blk * 8;
    const int b    = r0 >> 11;
    const int n0   = r0 & 2047;

    __shared__ float pt_s[8][4][64];
    __shared__ float whs[64][8];

    float wreg[64];
    {
        const float* Wp = W + (size_t)(w * 64) * 64 + lane;
#pragma unroll
        for (int kk = 0; kk < 64; kk++) wreg[kk] = Wp[(size_t)kk * 64];
    }

    const float* hbase = h + (size_t)r0 * 256 + w * 64;
    for (int rr = 0; rr < 8; rr++) {
        const float4* hp = (const float4*)(hbase + rr * 256);
        float acc = 0.f;
#pragma unroll
        for (int q = 0; q < 16; q++) {
            float4 hv = hp[q];
            acc += hv.x * wreg[4 * q + 0];
            acc += hv.y * wreg[4 * q + 1];
            acc += hv.z * wreg[4 * q + 2];
            acc += hv.w * wreg[4 * q + 3];
        }
        pt_s[rr][w][lane] = acc;
    }
    __syncthreads();

    const float a1 = a[lane];
    const float a2 = a[64 + lane];
#pragma unroll
    for (int rq = 0; rq < 2; rq++) {
        const int rr = w * 2 + rq;
        float v = pt_s[rr][0][lane] + pt_s[rr][1][lane] +
                  pt_s[rr][2][lane] + pt_s[rr][3][lane];
        whs[lane][rr] = v;
        float e1 = v * a1, e2 = v * a2;
#pragma unroll
        for (int d = 1; d < 64; d <<= 1) {
            e1 += __shfl_xor(e1, d);
            e2 += __shfl_xor(e2, d);
        }
        if (lane == 0) { esrc[r0 + rr] = e1; edst[r0 + rr] = e2; }
    }
    __syncthreads();

    if (tid < 128) {
        const int o = tid >> 1, hf = (tid & 1) * 4;
        float4 v = *(const float4*)&whs[o][hf];
        bf16x4 bv = { (__bf16)v.x, (__bf16)v.y, (__bf16)v.z, (__bf16)v.w };
        *(bf16x4*)(whT + (size_t)(b * 64 + o) * 2048 + n0 + hf) = bv;
    }
}

// ---------------- Kernel 2: fixed-max fused attention, 4 j-quarter waves ----------------
// Block: 256 thr = 4 waves over the SAME 16 rows; wave jg owns j in
// [jg*512, jg*512+512) = 8 tiles of 64. M_i = lrelu(esrc_i + max_j edst_j)
// is a row-wise upper bound (softmax shift-invariant) -> no running max,
// no rescale, no cross-lane reductions in the loop; merge = plain sum.
__global__ __launch_bounds__(256, 4)
void k2_attn(const int* __restrict__ adj, const __bf16* __restrict__ whT,
             const float* __restrict__ esrc, const float* __restrict__ edst,
             float* __restrict__ out) {
    const int tid  = threadIdx.x;
    const int lane = tid & 63;
    const int jg   = tid >> 6;          // j-quarter 0..3
    const int blk  = blockIdx.x;        // 0..1023
    const int b    = blk >> 7;
    const int i0   = (blk & 127) * 16;
    const int r    = lane & 15;
    const int hi   = lane >> 4;         // 0..3

    __shared__ float edst_s[2048];
    __shared__ float esrc_s[16];
    __shared__ float red_s[4];
    __shared__ float mrg_acc[3][1024];
    __shared__ float mrg_l[3][16];

    // ---- preamble: stage edst, block-wide max(edst), esrc ----
    float mymax = -3.0e38f;
#pragma unroll
    for (int q = 0; q < 2; q++) {
        float4 v = *(const float4*)&edst[b * 2048 + q * 1024 + tid * 4];
        *(float4*)&edst_s[q * 1024 + tid * 4] = v;
        mymax = fmaxf(fmaxf(mymax, v.x), fmaxf(v.y, fmaxf(v.z, v.w)));
    }
#pragma unroll
    for (int d = 1; d < 64; d <<= 1) mymax = fmaxf(mymax, __shfl_xor(mymax, d));
    if (lane == 0) red_s[jg] = mymax;
    if (tid < 16) esrc_s[tid] = esrc[b * 2048 + i0 + tid];
    __syncthreads();

    const float maxed = fmaxf(fmaxf(red_s[0], red_s[1]), fmaxf(red_s[2], red_s[3]));
    const float es = esrc_s[r];
    float M = es + maxed;
    M = fmaxf(M, 0.2f * M);             // lrelu (monotone) upper bound
    const float Mc = M * L2E;

    const int jbase = jg * 512;
    // lane (r,hi): adj row i0+r, cols jbase + t*64 + {8hi..+7, 32+8hi..+7}
    const int4* ap = (const int4*)(adj + (size_t)(b * 2048 + i0 + r) * 2048 +
                                   jbase + hi * 8);
    const __bf16* whTb = whT + (size_t)b * 64 * 2048 + (size_t)r * 2048 +
                         jbase + hi * 8;

    f32x4 lacc = {0.f, 0.f, 0.f, 0.f};
    f32x4 acc0 = {0.f,0.f,0.f,0.f}, acc1 = {0.f,0.f,0.f,0.f};
    f32x4 acc2 = {0.f,0.f,0.f,0.f}, acc3 = {0.f,0.f,0.f,0.f};

    int4 aA0 = ap[0],  aA1 = ap[1],  aA2 = ap[8],  aA3 = ap[9];
    int4 aB0 = ap[16], aB1 = ap[17], aB2 = ap[24], aB3 = ap[25];

// 4 score entries from one int4 A + one float4 E into p[base..base+3]
#define P4(A, E, base)                                                        \
    {                                                                         \
        float v;                                                              \
        v = es + E.x; v = fmaxf(v, 0.2f * v);                                 \
        p[base + 0] = A.x > 0 ? exp2f(__builtin_fmaf(v, L2E, -Mc)) : 0.f;     \
        v = es + E.y; v = fmaxf(v, 0.2f * v);                                 \
        p[base + 1] = A.y > 0 ? exp2f(__builtin_fmaf(v, L2E, -Mc)) : 0.f;     \
        v = es + E.z; v = fmaxf(v, 0.2f * v);                                 \
        p[base + 2] = A.z > 0 ? exp2f(__builtin_fmaf(v, L2E, -Mc)) : 0.f;     \
        v = es + E.w; v = fmaxf(v, 0.2f * v);                                 \
        p[base + 3] = A.w > 0 ? exp2f(__builtin_fmaf(v, L2E, -Mc)) : 0.f;     \
    }

#define TILE_BODY(T, A0, A1, A2, A3, PF)                                      \
    {                                                                         \
        const int jt = (T) * 64;                                              \
        const __bf16* wp = whTb + jt;                                         \
        bf16x8 B00 = *(const bf16x8*)(wp);                                    \
        bf16x8 B01 = *(const bf16x8*)(wp + 32);                               \
        bf16x8 B10 = *(const bf16x8*)(wp + 32768);                            \
        bf16x8 B11 = *(const bf16x8*)(wp + 32768 + 32);                       \
        bf16x8 B20 = *(const bf16x8*)(wp + 65536);                            \
        bf16x8 B21 = *(const bf16x8*)(wp + 65536 + 32);                       \
        bf16x8 B30 = *(const bf16x8*)(wp + 98304);                            \
        bf16x8 B31 = *(const bf16x8*)(wp + 98304 + 32);                       \
        float4 e0 = *(const float4*)&edst_s[jbase + jt + hi * 8];             \
        float4 e1 = *(const float4*)&edst_s[jbase + jt + hi * 8 + 4];         \
        float4 e2 = *(const float4*)&edst_s[jbase + jt + 32 + hi * 8];        \
        float4 e3 = *(const float4*)&edst_s[jbase + jt + 32 + hi * 8 + 4];    \
        float p[16];                                                          \
        P4(A0, e0, 0) P4(A1, e1, 4) P4(A2, e2, 8) P4(A3, e3, 12)              \
        if (PF) {                                                             \
            const int tn = ((T) + 2) * 16;                                    \
            A0 = ap[tn]; A1 = ap[tn + 1]; A2 = ap[tn + 8]; A3 = ap[tn + 9];   \
        }                                                                     \
        lacc[0] += p[0] + p[4] + p[8]  + p[12];                               \
        lacc[1] += p[1] + p[5] + p[9]  + p[13];                               \
        lacc[2] += p[2] + p[6] + p[10] + p[14];                               \
        lacc[3] += p[3] + p[7] + p[11] + p[15];                               \
        bf16x8 pa0, pa1;                                                      \
        _Pragma("unroll")                                                     \
        for (int e = 0; e < 8; e++) {                                         \
            pa0[e] = (__bf16)p[e];                                            \
            pa1[e] = (__bf16)p[e + 8];                                        \
        }                                                                     \
        mfma_bf16(pa0, B00, acc0); mfma_bf16(pa1, B01, acc0);                 \
        mfma_bf16(pa0, B10, acc1); mfma_bf16(pa1, B11, acc1);                 \
        mfma_bf16(pa0, B20, acc2); mfma_bf16(pa1, B21, acc2);                 \
        mfma_bf16(pa0, B30, acc3); mfma_bf16(pa1, B31, acc3);                 \
    }

    for (int t = 0; t < 8; t += 2) {
        TILE_BODY(t,     aA0, aA1, aA2, aA3, (t + 2 < 8));
        TILE_BODY(t + 1, aB0, aB1, aB2, aB3, (t + 3 < 8));
    }
#undef TILE_BODY
#undef P4

    // per-row l for this wave (rows spread over hi groups)
    float lsum = lacc[0] + lacc[1] + lacc[2] + lacc[3];
    lsum += __shfl_xor(lsum, 16);
    lsum += __shfl_xor(lsum, 32);

    // ---- cross-wave merge: plain sums (shared fixed M) ----
    if (jg > 0) {
        float* mb = mrg_acc[jg - 1];
        *(f32x4*)&mb[lane * 4]       = acc0;
        *(f32x4*)&mb[256 + lane * 4] = acc1;
        *(f32x4*)&mb[512 + lane * 4] = acc2;
        *(f32x4*)&mb[768 + lane * 4] = acc3;
        if (lane < 16) mrg_l[jg - 1][r] = lsum;
    }
    __syncthreads();
    if (jg == 0) {
        float ltot = lsum;
#pragma unroll
        for (int wv = 0; wv < 3; wv++) {
            const float* mb = mrg_acc[wv];
            acc0 += *(const f32x4*)&mb[lane * 4];
            acc1 += *(const f32x4*)&mb[256 + lane * 4];
            acc2 += *(const f32x4*)&mb[512 + lane * 4];
            acc3 += *(const f32x4*)&mb[768 + lane * 4];
            ltot += mrg_l[wv][r];
        }
#pragma unroll
        for (int reg = 0; reg < 4; reg++) {
            const float L  = __shfl(ltot, hi * 4 + reg);
            const float iL = 1.0f / L;
            float v0 = acc0[reg] * iL;
            float v1 = acc1[reg] * iL;
            float v2 = acc2[reg] * iL;
            float v3 = acc3[reg] * iL;
            v0 = v0 > 0.f ? v0 : expm1f(v0);
            v1 = v1 > 0.f ? v1 : expm1f(v1);
            v2 = v2 > 0.f ? v2 : expm1f(v2);
            v3 = v3 > 0.f ? v3 : expm1f(v3);
            float* op = out + (size_t)(b * 2048 + i0 + hi * 4 + reg) * 64 + r;
            op[0]  = v0;
            op[16] = v1;
            op[32] = v2;
            op[48] = v3;
        }
    }
}

extern "C" void kernel_launch(void* const* d_in, const int* in_sizes, int n_in,
                              void* d_out, int out_size, void* d_ws, size_t ws_size,
                              hipStream_t stream) {
    const float* h   = (const float*)d_in[0];
    const int*   adj = (const int*)d_in[1];
    const float* W   = (const float*)d_in[2];
    const float* a   = (const float*)d_in[3];
    float* out = (float*)d_out;

    __bf16* whT  = (__bf16*)d_ws;                                  // 2 MB
    float*  esrc = (float*)((char*)d_ws + (size_t)8 * 64 * 2048 * 2);
    float*  edst = esrc + 8 * 2048;

    hipLaunchKernelGGL(k1_wh, dim3(2048), dim3(256), 0, stream,
                       h, W, a, whT, esrc, edst);
    hipLaunchKernelGGL(k2_attn, dim3(1024), dim3(256), 0, stream,
                       adj, whT, esrc, edst, out);
}

// Round 5
// 89.804 us; speedup vs baseline: 1.2231x; 1.2231x over previous
//
#include <hip/hip_runtime.h>

#define L2E 1.44269504088896340736f

typedef float f32x4 __attribute__((ext_vector_type(4)));
typedef __bf16 bf16x8 __attribute__((ext_vector_type(8)));
typedef __bf16 bf16x4 __attribute__((ext_vector_type(4)));

// D(16x16)=A(16x32)*B(32x16)+C. A: lane l = row(l&15), k=8*(l>>4)+e.
// B: col(l&15), k=8*(l>>4)+e. C/D: col(l&15), row=4*(l>>4)+reg. [m89/m91]
__device__ inline void mfma_bf16(bf16x8 a, bf16x8 b, f32x4& c) {
    c = __builtin_amdgcn_mfma_f32_16x16x32_bf16(a, b, c, 0, 0, 0);
}

// ---------------- Kernel 1: Wh = h @ W, e_src, e_dst (unchanged) ----------------
__global__ __launch_bounds__(256, 2)
void k1_wh(const float* __restrict__ h, const float* __restrict__ W,
           const float* __restrict__ a, __bf16* __restrict__ whT,
           float* __restrict__ esrc, float* __restrict__ edst) {
    const int tid  = threadIdx.x;
    const int lane = tid & 63;
    const int w    = tid >> 6;
    const int blk  = blockIdx.x;
    const int r0   = blk * 8;
    const int b    = r0 >> 11;
    const int n0   = r0 & 2047;

    __shared__ float pt_s[8][4][64];
    __shared__ float whs[64][8];

    float wreg[64];
    {
        const float* Wp = W + (size_t)(w * 64) * 64 + lane;
#pragma unroll
        for (int kk = 0; kk < 64; kk++) wreg[kk] = Wp[(size_t)kk * 64];
    }

    const float* hbase = h + (size_t)r0 * 256 + w * 64;
    for (int rr = 0; rr < 8; rr++) {
        const float4* hp = (const float4*)(hbase + rr * 256);
        float acc = 0.f;
#pragma unroll
        for (int q = 0; q < 16; q++) {
            float4 hv = hp[q];
            acc += hv.x * wreg[4 * q + 0];
            acc += hv.y * wreg[4 * q + 1];
            acc += hv.z * wreg[4 * q + 2];
            acc += hv.w * wreg[4 * q + 3];
        }
        pt_s[rr][w][lane] = acc;
    }
    __syncthreads();

    const float a1 = a[lane];
    const float a2 = a[64 + lane];
#pragma unroll
    for (int rq = 0; rq < 2; rq++) {
        const int rr = w * 2 + rq;
        float v = pt_s[rr][0][lane] + pt_s[rr][1][lane] +
                  pt_s[rr][2][lane] + pt_s[rr][3][lane];
        whs[lane][rr] = v;
        float e1 = v * a1, e2 = v * a2;
#pragma unroll
        for (int d = 1; d < 64; d <<= 1) {
            e1 += __shfl_xor(e1, d);
            e2 += __shfl_xor(e2, d);
        }
        if (lane == 0) { esrc[r0 + rr] = e1; edst[r0 + rr] = e2; }
    }
    __syncthreads();

    if (tid < 128) {
        const int o = tid >> 1, hf = (tid & 1) * 4;
        float4 v = *(const float4*)&whs[o][hf];
        bf16x4 bv = { (__bf16)v.x, (__bf16)v.y, (__bf16)v.z, (__bf16)v.w };
        *(bf16x4*)(whT + (size_t)(b * 64 + o) * 2048 + n0 + hf) = bv;
    }
}

// ---------------- Kernel 2: fixed-max fused attention, 4 j-quarter waves ----------------
// Block: 256 thr = 4 waves over the SAME 16 rows; wave jg owns j in
// [jg*512, jg*512+512) = 8 tiles of 64. M_i = lrelu(esrc_i + max_j edst_j)
// is a row-wise upper bound (softmax shift-invariant) -> no running max,
// no rescale, no cross-lane reductions in the loop; merge = plain sum.
// launch_bounds min-waves = 2 (NOT 4): the 128-reg budget at 4 forced a
// 64-VGPR clamp + ~230 MB scratch spill traffic (round-4 regression).
__global__ __launch_bounds__(256, 2)
void k2_attn(const int* __restrict__ adj, const __bf16* __restrict__ whT,
             const float* __restrict__ esrc, const float* __restrict__ edst,
             float* __restrict__ out) {
    const int tid  = threadIdx.x;
    const int lane = tid & 63;
    const int jg   = tid >> 6;          // j-quarter 0..3
    const int blk  = blockIdx.x;        // 0..1023
    const int b    = blk >> 7;
    const int i0   = (blk & 127) * 16;
    const int r    = lane & 15;
    const int hi   = lane >> 4;         // 0..3

    __shared__ float edst_s[2048];
    __shared__ float esrc_s[16];
    __shared__ float red_s[4];
    __shared__ float mrg_acc[3][1024];
    __shared__ float mrg_l[3][16];

    // ---- preamble: stage edst, block-wide max(edst), esrc ----
    float mymax = -3.0e38f;
#pragma unroll
    for (int q = 0; q < 2; q++) {
        float4 v = *(const float4*)&edst[b * 2048 + q * 1024 + tid * 4];
        *(float4*)&edst_s[q * 1024 + tid * 4] = v;
        mymax = fmaxf(fmaxf(mymax, v.x), fmaxf(v.y, fmaxf(v.z, v.w)));
    }
#pragma unroll
    for (int d = 1; d < 64; d <<= 1) mymax = fmaxf(mymax, __shfl_xor(mymax, d));
    if (lane == 0) red_s[jg] = mymax;
    if (tid < 16) esrc_s[tid] = esrc[b * 2048 + i0 + tid];
    __syncthreads();

    const float maxed = fmaxf(fmaxf(red_s[0], red_s[1]), fmaxf(red_s[2], red_s[3]));
    const float es = esrc_s[r];
    float M = es + maxed;
    M = fmaxf(M, 0.2f * M);             // lrelu (monotone) upper bound
    const float Mc = M * L2E;

    const int jbase = jg * 512;
    // lane (r,hi): adj row i0+r, cols jbase + t*64 + {8hi..+7, 32+8hi..+7}
    const int4* ap = (const int4*)(adj + (size_t)(b * 2048 + i0 + r) * 2048 +
                                   jbase + hi * 8);
    const __bf16* whTb = whT + (size_t)b * 64 * 2048 + (size_t)r * 2048 +
                         jbase + hi * 8;

    f32x4 lacc = {0.f, 0.f, 0.f, 0.f};
    f32x4 acc0 = {0.f,0.f,0.f,0.f}, acc1 = {0.f,0.f,0.f,0.f};
    f32x4 acc2 = {0.f,0.f,0.f,0.f}, acc3 = {0.f,0.f,0.f,0.f};

    int4 aA0 = ap[0],  aA1 = ap[1],  aA2 = ap[8],  aA3 = ap[9];
    int4 aB0 = ap[16], aB1 = ap[17], aB2 = ap[24], aB3 = ap[25];

// 4 score entries from one int4 A + one float4 E into p[base..base+3]
#define P4(A, E, base)                                                        \
    {                                                                         \
        float v;                                                              \
        v = es + E.x; v = fmaxf(v, 0.2f * v);                                 \
        p[base + 0] = A.x > 0 ? exp2f(__builtin_fmaf(v, L2E, -Mc)) : 0.f;     \
        v = es + E.y; v = fmaxf(v, 0.2f * v);                                 \
        p[base + 1] = A.y > 0 ? exp2f(__builtin_fmaf(v, L2E, -Mc)) : 0.f;     \
        v = es + E.z; v = fmaxf(v, 0.2f * v);                                 \
        p[base + 2] = A.z > 0 ? exp2f(__builtin_fmaf(v, L2E, -Mc)) : 0.f;     \
        v = es + E.w; v = fmaxf(v, 0.2f * v);                                 \
        p[base + 3] = A.w > 0 ? exp2f(__builtin_fmaf(v, L2E, -Mc)) : 0.f;     \
    }

#define TILE_BODY(T, A0, A1, A2, A3, PF)                                      \
    {                                                                         \
        const int jt = (T) * 64;                                              \
        const __bf16* wp = whTb + jt;                                         \
        bf16x8 B00 = *(const bf16x8*)(wp);                                    \
        bf16x8 B01 = *(const bf16x8*)(wp + 32);                               \
        bf16x8 B10 = *(const bf16x8*)(wp + 32768);                            \
        bf16x8 B11 = *(const bf16x8*)(wp + 32768 + 32);                       \
        bf16x8 B20 = *(const bf16x8*)(wp + 65536);                            \
        bf16x8 B21 = *(const bf16x8*)(wp + 65536 + 32);                       \
        bf16x8 B30 = *(const bf16x8*)(wp + 98304);                            \
        bf16x8 B31 = *(const bf16x8*)(wp + 98304 + 32);                       \
        float4 e0 = *(const float4*)&edst_s[jbase + jt + hi * 8];             \
        float4 e1 = *(const float4*)&edst_s[jbase + jt + hi * 8 + 4];         \
        float4 e2 = *(const float4*)&edst_s[jbase + jt + 32 + hi * 8];        \
        float4 e3 = *(const float4*)&edst_s[jbase + jt + 32 + hi * 8 + 4];    \
        float p[16];                                                          \
        P4(A0, e0, 0) P4(A1, e1, 4) P4(A2, e2, 8) P4(A3, e3, 12)              \
        if (PF) {                                                             \
            const int tn = ((T) + 2) * 16;                                    \
            A0 = ap[tn]; A1 = ap[tn + 1]; A2 = ap[tn + 8]; A3 = ap[tn + 9];   \
        }                                                                     \
        lacc[0] += p[0] + p[4] + p[8]  + p[12];                               \
        lacc[1] += p[1] + p[5] + p[9]  + p[13];                               \
        lacc[2] += p[2] + p[6] + p[10] + p[14];                               \
        lacc[3] += p[3] + p[7] + p[11] + p[15];                               \
        bf16x8 pa0, pa1;                                                      \
        _Pragma("unroll")                                                     \
        for (int e = 0; e < 8; e++) {                                         \
            pa0[e] = (__bf16)p[e];                                            \
            pa1[e] = (__bf16)p[e + 8];                                        \
        }                                                                     \
        mfma_bf16(pa0, B00, acc0); mfma_bf16(pa1, B01, acc0);                 \
        mfma_bf16(pa0, B10, acc1); mfma_bf16(pa1, B11, acc1);                 \
        mfma_bf16(pa0, B20, acc2); mfma_bf16(pa1, B21, acc2);                 \
        mfma_bf16(pa0, B30, acc3); mfma_bf16(pa1, B31, acc3);                 \
    }

    for (int t = 0; t < 8; t += 2) {
        TILE_BODY(t,     aA0, aA1, aA2, aA3, (t + 2 < 8));
        TILE_BODY(t + 1, aB0, aB1, aB2, aB3, (t + 3 < 8));
    }
#undef TILE_BODY
#undef P4

    // per-row l for this wave (rows spread over hi groups)
    float lsum = lacc[0] + lacc[1] + lacc[2] + lacc[3];
    lsum += __shfl_xor(lsum, 16);
    lsum += __shfl_xor(lsum, 32);

    // ---- cross-wave merge: plain sums (shared fixed M) ----
    if (jg > 0) {
        float* mb = mrg_acc[jg - 1];
        *(f32x4*)&mb[lane * 4]       = acc0;
        *(f32x4*)&mb[256 + lane * 4] = acc1;
        *(f32x4*)&mb[512 + lane * 4] = acc2;
        *(f32x4*)&mb[768 + lane * 4] = acc3;
        if (lane < 16) mrg_l[jg - 1][r] = lsum;
    }
    __syncthreads();
    if (jg == 0) {
        float ltot = lsum;
#pragma unroll
        for (int wv = 0; wv < 3; wv++) {
            const float* mb = mrg_acc[wv];
            acc0 += *(const f32x4*)&mb[lane * 4];
            acc1 += *(const f32x4*)&mb[256 + lane * 4];
            acc2 += *(const f32x4*)&mb[512 + lane * 4];
            acc3 += *(const f32x4*)&mb[768 + lane * 4];
            ltot += mrg_l[wv][r];
        }
#pragma unroll
        for (int reg = 0; reg < 4; reg++) {
            const float L  = __shfl(ltot, hi * 4 + reg);
            const float iL = 1.0f / L;
            float v0 = acc0[reg] * iL;
            float v1 = acc1[reg] * iL;
            float v2 = acc2[reg] * iL;
            float v3 = acc3[reg] * iL;
            v0 = v0 > 0.f ? v0 : expm1f(v0);
            v1 = v1 > 0.f ? v1 : expm1f(v1);
            v2 = v2 > 0.f ? v2 : expm1f(v2);
            v3 = v3 > 0.f ? v3 : expm1f(v3);
            float* op = out + (size_t)(b * 2048 + i0 + hi * 4 + reg) * 64 + r;
            op[0]  = v0;
            op[16] = v1;
            op[32] = v2;
            op[48] = v3;
        }
    }
}

extern "C" void kernel_launch(void* const* d_in, const int* in_sizes, int n_in,
                              void* d_out, int out_size, void* d_ws, size_t ws_size,
                              hipStream_t stream) {
    const float* h   = (const float*)d_in[0];
    const int*   adj = (const int*)d_in[1];
    const float* W   = (const float*)d_in[2];
    const float* a   = (const float*)d_in[3];
    float* out = (float*)d_out;

    __bf16* whT  = (__bf16*)d_ws;                                  // 2 MB
    float*  esrc = (float*)((char*)d_ws + (size_t)8 * 64 * 2048 * 2);
    float*  edst = esrc + 8 * 2048;

    hipLaunchKernelGGL(k1_wh, dim3(2048), dim3(256), 0, stream,
                       h, W, a, whT, esrc, edst);
    hipLaunchKernelGGL(k2_attn, dim3(1024), dim3(256), 0, stream,
                       adj, whT, esrc, edst, out);
}

// Round 6
// 69.085 us; speedup vs baseline: 1.5899x; 1.2999x over previous
//
#include <hip/hip_runtime.h>

#define L2E 1.44269504088896340736f

typedef float f32x4 __attribute__((ext_vector_type(4)));
typedef __bf16 bf16x8 __attribute__((ext_vector_type(8)));
typedef __bf16 bf16x4 __attribute__((ext_vector_type(4)));

// D(16x16)=A(16x32)*B(32x16)+C. A: lane l = row(l&15), k=8*(l>>4)+e.
// B: col(l&15), k=8*(l>>4)+e. C/D: col(l&15), row=4*(l>>4)+reg. [m89/m91]
__device__ inline void mfma_bf16(bf16x8 a, bf16x8 b, f32x4& c) {
    c = __builtin_amdgcn_mfma_f32_16x16x32_bf16(a, b, c, 0, 0, 0);
}

// whP layout (tile-major so k2's B-frag loads are wave-contiguous 1KB):
// whP[b][t=j/64][kh=(j/32)&1][ob=o/16][hi=(j/8)&3][r=o&15][e=j&7], bf16.
// per-b size = 32*2*4*4*128 = 131072 elems (256KB).

// ---------------- Kernel 1: Wh = h @ W, e_src, e_dst ----------------
__global__ __launch_bounds__(256, 2)
void k1_wh(const float* __restrict__ h, const float* __restrict__ W,
           const float* __restrict__ a, __bf16* __restrict__ whP,
           float* __restrict__ esrc, float* __restrict__ edst) {
    const int tid  = threadIdx.x;
    const int lane = tid & 63;
    const int w    = tid >> 6;
    const int blk  = blockIdx.x;
    const int r0   = blk * 8;
    const int b    = r0 >> 11;
    const int n0   = r0 & 2047;

    __shared__ float pt_s[8][4][64];
    __shared__ float whs[64][8];

    float wreg[64];
    {
        const float* Wp = W + (size_t)(w * 64) * 64 + lane;
#pragma unroll
        for (int kk = 0; kk < 64; kk++) wreg[kk] = Wp[(size_t)kk * 64];
    }

    const float* hbase = h + (size_t)r0 * 256 + w * 64;
    for (int rr = 0; rr < 8; rr++) {
        const float4* hp = (const float4*)(hbase + rr * 256);
        float acc = 0.f;
#pragma unroll
        for (int q = 0; q < 16; q++) {
            float4 hv = hp[q];
            acc += hv.x * wreg[4 * q + 0];
            acc += hv.y * wreg[4 * q + 1];
            acc += hv.z * wreg[4 * q + 2];
            acc += hv.w * wreg[4 * q + 3];
        }
        pt_s[rr][w][lane] = acc;
    }
    __syncthreads();

    const float a1 = a[lane];
    const float a2 = a[64 + lane];
#pragma unroll
    for (int rq = 0; rq < 2; rq++) {
        const int rr = w * 2 + rq;
        float v = pt_s[rr][0][lane] + pt_s[rr][1][lane] +
                  pt_s[rr][2][lane] + pt_s[rr][3][lane];
        whs[lane][rr] = v;
        float e1 = v * a1, e2 = v * a2;
#pragma unroll
        for (int d = 1; d < 64; d <<= 1) {
            e1 += __shfl_xor(e1, d);
            e2 += __shfl_xor(e2, d);
        }
        if (lane == 0) { esrc[r0 + rr] = e1; edst[r0 + rr] = e2; }
    }
    __syncthreads();

    if (tid < 128) {
        const int o  = tid >> 1, hf = (tid & 1) * 4;
        float4 v = *(const float4*)&whs[o][hf];
        bf16x4 bv = { (__bf16)v.x, (__bf16)v.y, (__bf16)v.z, (__bf16)v.w };
        const int t   = n0 >> 6;
        const int kh  = (n0 >> 5) & 1;
        const int hi2 = (n0 >> 3) & 3;
        const int ob  = o >> 4;
        const int rr  = o & 15;
        const size_t flat =
            ((((size_t)(b * 32 + t) * 2 + kh) * 4 + ob) * 4 + hi2) * 128 +
            rr * 8 + hf;
        *(bf16x4*)(whP + flat) = bv;
    }
}

// ---------------- Kernel 2: fixed-max fused attention, ballot adj ----------------
// Block: 256 thr = 4 waves over the SAME 16 rows; wave jg owns j in
// [jg*512, jg*512+512) = 8 tiles of 64. adj read via 16 COALESCED dword
// loads per tile + __ballot -> per-row 64-bit mask (fixes scattered-VMEM
// MLP starvation: every VMEM instr is now 1 contiguous segment).
__global__ __launch_bounds__(256, 2)
void k2_attn(const int* __restrict__ adj, const __bf16* __restrict__ whP,
             const float* __restrict__ esrc, const float* __restrict__ edst,
             float* __restrict__ out) {
    const int tid  = threadIdx.x;
    const int lane = tid & 63;
    const int jg   = tid >> 6;          // j-quarter 0..3
    const int blk  = blockIdx.x;        // 0..1023
    const int b    = blk >> 7;
    const int i0   = (blk & 127) * 16;
    const int r    = lane & 15;
    const int hi   = lane >> 4;         // 0..3

    __shared__ float edst_s[2048];
    __shared__ float esrc_s[16];
    __shared__ float red_s[4];
    __shared__ float mrg_acc[3][1024];
    __shared__ float mrg_l[3][16];

    // ---- preamble: stage edst, block-wide max(edst), esrc ----
    float mymax = -3.0e38f;
#pragma unroll
    for (int q = 0; q < 2; q++) {
        float4 v = *(const float4*)&edst[b * 2048 + q * 1024 + tid * 4];
        *(float4*)&edst_s[q * 1024 + tid * 4] = v;
        mymax = fmaxf(fmaxf(mymax, v.x), fmaxf(v.y, fmaxf(v.z, v.w)));
    }
#pragma unroll
    for (int d = 1; d < 64; d <<= 1) mymax = fmaxf(mymax, __shfl_xor(mymax, d));
    if (lane == 0) red_s[jg] = mymax;
    if (tid < 16) esrc_s[tid] = esrc[b * 2048 + i0 + tid];
    __syncthreads();

    const float maxed = fmaxf(fmaxf(red_s[0], red_s[1]), fmaxf(red_s[2], red_s[3]));
    const float es = esrc_s[r];
    float M = es + maxed;
    M = fmaxf(M, 0.2f * M);             // lrelu (monotone) upper bound
    const float Mc = M * L2E;

    const int jbase = jg * 512;
    // coalesced adj: lane l reads adj[row, jbase + jt + l]
    const int* abase = adj + (size_t)(b * 2048 + i0) * 2048 + jbase + lane;
    const __bf16* wbase = whP + (size_t)b * 131072 +
                          (size_t)(jg * 8) * 4096 + lane * 8;

    f32x4 lacc = {0.f, 0.f, 0.f, 0.f};
    f32x4 acc0 = {0.f,0.f,0.f,0.f}, acc1 = {0.f,0.f,0.f,0.f};
    f32x4 acc2 = {0.f,0.f,0.f,0.f}, acc3 = {0.f,0.f,0.f,0.f};

// 4 p-entries from float4 E and mask bits (bits>>sh)&0..3
#define PB(E, bits, sh, base)                                                 \
    {                                                                         \
        const unsigned bb = (bits) >> (sh);                                   \
        float v;                                                              \
        v = es + E.x; v = fmaxf(v, 0.2f * v);                                 \
        p[base + 0] = (bb & 1u) ? exp2f(__builtin_fmaf(v, L2E, -Mc)) : 0.f;   \
        v = es + E.y; v = fmaxf(v, 0.2f * v);                                 \
        p[base + 1] = (bb & 2u) ? exp2f(__builtin_fmaf(v, L2E, -Mc)) : 0.f;   \
        v = es + E.z; v = fmaxf(v, 0.2f * v);                                 \
        p[base + 2] = (bb & 4u) ? exp2f(__builtin_fmaf(v, L2E, -Mc)) : 0.f;   \
        v = es + E.w; v = fmaxf(v, 0.2f * v);                                 \
        p[base + 3] = (bb & 8u) ? exp2f(__builtin_fmaf(v, L2E, -Mc)) : 0.f;   \
    }

    for (int tl = 0; tl < 8; ++tl) {
        const int jt = tl * 64;
        // ---- 16 coalesced adj row loads (256B segments) ----
        int av[16];
#pragma unroll
        for (int rr2 = 0; rr2 < 16; rr2++)
            av[rr2] = abase[(size_t)rr2 * 2048 + jt];
        // ---- 8 wave-contiguous whP loads (1KB each, L2-resident) ----
        const __bf16* wb = wbase + (size_t)tl * 4096;
        bf16x8 B00 = *(const bf16x8*)(wb);              // kh0 ob0
        bf16x8 B01 = *(const bf16x8*)(wb + 512);        // kh0 ob1
        bf16x8 B02 = *(const bf16x8*)(wb + 1024);       // kh0 ob2
        bf16x8 B03 = *(const bf16x8*)(wb + 1536);       // kh0 ob3
        bf16x8 B10 = *(const bf16x8*)(wb + 2048);       // kh1 ob0
        bf16x8 B11 = *(const bf16x8*)(wb + 2560);       // kh1 ob1
        bf16x8 B12 = *(const bf16x8*)(wb + 3072);       // kh1 ob2
        bf16x8 B13 = *(const bf16x8*)(wb + 3584);       // kh1 ob3
        // ---- ballots -> this lane's row mask ----
        unsigned int mlo = 0u, mhi = 0u;
#pragma unroll
        for (int rr2 = 0; rr2 < 16; rr2++) {
            unsigned long long bal = __ballot(av[rr2] > 0);
            if (r == rr2) { mlo = (unsigned int)bal;
                            mhi = (unsigned int)(bal >> 32); }
        }
        const unsigned int blo = mlo >> (hi * 8);
        const unsigned int bhi = mhi >> (hi * 8);
        // ---- scores -> p ----
        float4 e0 = *(const float4*)&edst_s[jbase + jt + hi * 8];
        float4 e1 = *(const float4*)&edst_s[jbase + jt + hi * 8 + 4];
        float4 e2 = *(const float4*)&edst_s[jbase + jt + 32 + hi * 8];
        float4 e3 = *(const float4*)&edst_s[jbase + jt + 32 + hi * 8 + 4];
        float p[16];
        PB(e0, blo, 0, 0) PB(e1, blo, 4, 4) PB(e2, bhi, 0, 8) PB(e3, bhi, 4, 12)
        lacc[0] += p[0] + p[4] + p[8]  + p[12];
        lacc[1] += p[1] + p[5] + p[9]  + p[13];
        lacc[2] += p[2] + p[6] + p[10] + p[14];
        lacc[3] += p[3] + p[7] + p[11] + p[15];
        bf16x8 pa0, pa1;
#pragma unroll
        for (int e = 0; e < 8; e++) {
            pa0[e] = (__bf16)p[e];
            pa1[e] = (__bf16)p[e + 8];
        }
        mfma_bf16(pa0, B00, acc0); mfma_bf16(pa1, B10, acc0);
        mfma_bf16(pa0, B01, acc1); mfma_bf16(pa1, B11, acc1);
        mfma_bf16(pa0, B02, acc2); mfma_bf16(pa1, B12, acc2);
        mfma_bf16(pa0, B03, acc3); mfma_bf16(pa1, B13, acc3);
    }
#undef PB

    // per-row l for this wave
    float lsum = lacc[0] + lacc[1] + lacc[2] + lacc[3];
    lsum += __shfl_xor(lsum, 16);
    lsum += __shfl_xor(lsum, 32);

    // ---- cross-wave merge: plain sums (shared fixed M) ----
    if (jg > 0) {
        float* mb = mrg_acc[jg - 1];
        *(f32x4*)&mb[lane * 4]       = acc0;
        *(f32x4*)&mb[256 + lane * 4] = acc1;
        *(f32x4*)&mb[512 + lane * 4] = acc2;
        *(f32x4*)&mb[768 + lane * 4] = acc3;
        if (lane < 16) mrg_l[jg - 1][r] = lsum;
    }
    __syncthreads();
    if (jg == 0) {
        float ltot = lsum;
#pragma unroll
        for (int wv = 0; wv < 3; wv++) {
            const float* mb = mrg_acc[wv];
            acc0 += *(const f32x4*)&mb[lane * 4];
            acc1 += *(const f32x4*)&mb[256 + lane * 4];
            acc2 += *(const f32x4*)&mb[512 + lane * 4];
            acc3 += *(const f32x4*)&mb[768 + lane * 4];
            ltot += mrg_l[wv][r];
        }
#pragma unroll
        for (int reg = 0; reg < 4; reg++) {
            const float L  = __shfl(ltot, hi * 4 + reg);
            const float iL = 1.0f / L;
            float v0 = acc0[reg] * iL;
            float v1 = acc1[reg] * iL;
            float v2 = acc2[reg] * iL;
            float v3 = acc3[reg] * iL;
            v0 = v0 > 0.f ? v0 : expm1f(v0);
            v1 = v1 > 0.f ? v1 : expm1f(v1);
            v2 = v2 > 0.f ? v2 : expm1f(v2);
            v3 = v3 > 0.f ? v3 : expm1f(v3);
            float* op = out + (size_t)(b * 2048 + i0 + hi * 4 + reg) * 64 + r;
            op[0]  = v0;
            op[16] = v1;
            op[32] = v2;
            op[48] = v3;
        }
    }
}

extern "C" void kernel_launch(void* const* d_in, const int* in_sizes, int n_in,
                              void* d_out, int out_size, void* d_ws, size_t ws_size,
                              hipStream_t stream) {
    const float* h   = (const float*)d_in[0];
    const int*   adj = (const int*)d_in[1];
    const float* W   = (const float*)d_in[2];
    const float* a   = (const float*)d_in[3];
    float* out = (float*)d_out;

    __bf16* whP  = (__bf16*)d_ws;                                  // 2 MB
    float*  esrc = (float*)((char*)d_ws + (size_t)8 * 131072 * 2);
    float*  edst = esrc + 8 * 2048;

    hipLaunchKernelGGL(k1_wh, dim3(2048), dim3(256), 0, stream,
                       h, W, a, whP, esrc, edst);
    hipLaunchKernelGGL(k2_attn, dim3(1024), dim3(256), 0, stream,
                       adj, whP, esrc, edst, out);
}